// Round 6
// baseline (46.093 us; speedup 1.0000x reference)
//
#include <hip/hip_runtime.h>

// MultiHeadAttention — fused per-token head-mixing attention.
// B=32, S=2048 -> 65536 tokens; E=128; HEADS=32; HEAD_DIM=4.
// out[t] = softmax_over_kh( Q(t)K(t)^T * 0.5 ) V(t)  @ Wo^T + bo.
//
// R6 (from 46us R5): attack the latency bound (VGPR=52 showed serialized
// phase-2 chains; MfmaUtil 12%, VALUBusy 40%).
//  - Phase 2: manual 2-token interleave (sc0/sc1, pv0/pv1 named) -> 2
//    independent MFMA chains in flight. exp2 applied directly (0.5*log2e
//    folded into Wk at pack time -> 16 fewer v_mul/token).
//  - Phase 1/3 operand swap (A=W, B=x; kappa-symmetric fragments, proven by
//    phase 2 which already swaps): C[m=w_row][n=token] -> Q/K stores are one
//    ds_write_b64 (was 4x b16), phase-3 out stores are dwordx4 (was 4x dword).
//  - All-f16 pipeline (cvt_pkrtz instead of 4-inst bf16 bit-math).
//  - attended aliases qs (each token's Q read before its attended write, same
//    wave) -> LDS 13056 B, 12 blocks/CU capacity.
//  - NO min-waves launch-bounds clause (R2 lesson: forced VGPR=64 -> spills).

#define TOKENS (32 * 2048)
#define E 128
#define NH 32
#define BT 16           // tokens per block
#define THREADS 128     // 2 waves
#define LPITCH 136      // f16 elems per LDS token row (272 B)

typedef __attribute__((ext_vector_type(4))) float f32x4;
typedef __attribute__((ext_vector_type(16))) float f32x16;
typedef __fp16 h8_t __attribute__((ext_vector_type(8)));

#if __has_builtin(__builtin_amdgcn_exp2f)
#define EXP2F __builtin_amdgcn_exp2f
#else
#define EXP2F exp2f
#endif

#if __has_builtin(__builtin_amdgcn_rcpf)
#define RCPF __builtin_amdgcn_rcpf
#else
#define RCPF(x) (1.0f / (x))
#endif

static __device__ __forceinline__ unsigned pk16(float a, float b) {
    return __builtin_bit_cast(unsigned, __builtin_amdgcn_cvt_pkrtz(a, b));
}

static __device__ __forceinline__ f32x16 zero16() {
    f32x16 z;
#pragma unroll
    for (int i = 0; i < 16; ++i) z[i] = 0.f;
    return z;
}

// V' LDS permutation: p(kh) groups the 8 kh needed by PV A-fragment lane
// (c32,gg) half h into one contiguous 16B run at halfword offset d*32+16h+8gg.
static __device__ __forceinline__ int vperm(int kh) {
    return ((kh >> 4) & 1) * 16 + ((kh >> 2) & 1) * 8 + ((kh >> 3) & 1) * 4 + (kh & 3);
}

// ---------------------------------------------------------------------------
// Prelude: pack Wq,Wk,Wv,Wo (fp32, [out=128][in=128]) into f16 MFMA fragment
// order: wpk[proj][nt(8)][ks(4)][lane(64)][j(8)]; for lane l (c=l&15, g=l>>4):
// elem j = W[nt*16+c][ks*32 + g*8 + j].  Wk is pre-scaled by 0.5*log2(e) so
// phase 2's exp2 needs no multiply.
// ---------------------------------------------------------------------------
__global__ void pack_w(const float* __restrict__ Wq, const float* __restrict__ Wk,
                       const float* __restrict__ Wv, const float* __restrict__ Wo,
                       __fp16* __restrict__ wpk) {
    int idx = blockIdx.x * blockDim.x + threadIdx.x;   // 4*8*4*64 = 8192
    if (idx >= 4 * 8 * 4 * 64) return;
    int lane = idx & 63;
    int ks   = (idx >> 6) & 3;
    int nt   = (idx >> 8) & 7;
    int proj = idx >> 11;
    const float* W = (proj == 0) ? Wq : (proj == 1) ? Wk : (proj == 2) ? Wv : Wo;
    float scl = (proj == 1) ? 0.72134752044448170f : 1.0f;  // 0.5*log2(e)
    int c = lane & 15, g = lane >> 4;
    const float* src = W + (size_t)(nt * 16 + c) * E + ks * 32 + g * 8;
    __fp16* dst = wpk + (size_t)idx * 8;
#pragma unroll
    for (int j = 0; j < 8; ++j) dst[j] = (__fp16)(src[j] * scl);
}

// ---------------------------------------------------------------------------
// Main fused kernel: 16 tokens per block, 2 waves.
// ---------------------------------------------------------------------------
__global__ __launch_bounds__(THREADS) void mha_fused(
        const float* __restrict__ x, const __fp16* __restrict__ wpk,
        const float* __restrict__ bo, float* __restrict__ out) {
    __shared__ __align__(16) __fp16 qs [BT * LPITCH];  // Q rows, then attended
    __shared__ __align__(16) __fp16 ksh[BT * LPITCH];  // K*cexp rows [tok][kh*4+d]
    __shared__ __align__(16) __fp16 vth[BT * LPITCH];  // V'' [tok][d*32+p(kh)]

    const int tid  = threadIdx.x;
    const int wave = tid >> 6;
    const int lane = tid & 63;
    const int c = lane & 15, g = lane >> 4;
    const int bt0 = blockIdx.x * BT;

    // ---------------- Phase 1: Q,K,V projections (A=W, B=x swap) -----------
    {
        // B fragments: x rows -> f16, lane c = token, kappa(g,j)=g*8+j
        h8_t afrag[4];
        const float* xrow = x + (size_t)(bt0 + c) * E;
#pragma unroll
        for (int ks2 = 0; ks2 < 4; ++ks2) {
            const float* p = xrow + ks2 * 32 + g * 8;
            float4 v0 = *(const float4*)(p);
            float4 v1 = *(const float4*)(p + 4);
            uint4 au;
            au.x = pk16(v0.x, v0.y);
            au.y = pk16(v0.z, v0.w);
            au.z = pk16(v1.x, v1.y);
            au.w = pk16(v1.z, v1.w);
            afrag[ks2] = __builtin_bit_cast(h8_t, au);
        }

        // nc = 2*i + wave  ->  proj = i>>2 (compile-time), nt covers evens/odds
#pragma unroll
        for (int i = 0; i < 12; ++i) {
            int nc   = i * 2 + wave;
            int proj = i >> 2;            // 0:Q 1:K 2:V
            int nt   = nc & 7;
            const __fp16* wb = wpk + ((size_t)((proj * 8 + nt) * 4) * 64 + lane) * 8;
            f32x4 acc = {0.f, 0.f, 0.f, 0.f};
#pragma unroll
            for (int ks2 = 0; ks2 < 4; ++ks2) {
                h8_t wf = *(const h8_t*)(wb + (size_t)ks2 * 64 * 8);
                // A=W (m=w_row), B=x (n=token): C[m=g*4+r2 (+nt*16)][n=c]
                acc = __builtin_amdgcn_mfma_f32_16x16x32_f16(wf, afrag[ks2], acc, 0, 0, 0);
            }
            if (proj < 2) {
                __fp16* dst = proj ? ksh : qs;
                uint2 st = make_uint2(pk16(acc[0], acc[1]), pk16(acc[2], acc[3]));
                *(uint2*)(dst + c * LPITCH + nt * 16 + g * 4) = st;   // one b64
            } else {
                int vp = vperm(nt * 4 + g);   // kh = nt*4+g, d = r2
#pragma unroll
                for (int r2 = 0; r2 < 4; ++r2)
                    vth[c * LPITCH + r2 * 32 + vp] = (__fp16)acc[r2];
            }
        }
    }
    __syncthreads();

    // ---------------- Phase 2: per-token attention, 2-token ILP ------------
    // S^T[kh][qh] = mfma32x32(A=K', B=Q) (k=d in slots 0-3);
    // O/denom     = mfma32x32(A=V'+ones-row4, B=exp(S)) x2 halves.
    {
        const int c32 = lane & 31;
        const int gg  = lane >> 5;
        const uint4 ONES4 = make_uint4(0x3C003C00u, 0x3C003C00u, 0x3C003C00u, 0x3C003C00u);
        const f32x16 z = zero16();
        const int tb = wave * 8;
#pragma unroll 1
        for (int pr = 0; pr < 4; ++pr) {
            const int t0 = tb + pr * 2, t1 = t0 + 1;
            const __fp16* v0r = vth + t0 * LPITCH;
            const __fp16* v1r = vth + t1 * LPITCH;

            uint4 ka0 = {0u,0u,0u,0u}, qa0 = {0u,0u,0u,0u};
            uint4 ka1 = {0u,0u,0u,0u}, qa1 = {0u,0u,0u,0u};
            if (gg == 0) {
                uint2 t;
                t = *(const uint2*)(ksh + t0 * LPITCH + c32 * 4); ka0.x = t.x; ka0.y = t.y;
                t = *(const uint2*)(qs  + t0 * LPITCH + c32 * 4); qa0.x = t.x; qa0.y = t.y;
                t = *(const uint2*)(ksh + t1 * LPITCH + c32 * 4); ka1.x = t.x; ka1.y = t.y;
                t = *(const uint2*)(qs  + t1 * LPITCH + c32 * 4); qa1.x = t.x; qa1.y = t.y;
            }
            uint4 va00 = *(const uint4*)(v0r + (c32 & 3) * 32 + gg * 8);
            uint4 va01 = *(const uint4*)(v0r + (c32 & 3) * 32 + 16 + gg * 8);
            uint4 va10 = *(const uint4*)(v1r + (c32 & 3) * 32 + gg * 8);
            uint4 va11 = *(const uint4*)(v1r + (c32 & 3) * 32 + 16 + gg * 8);
            if (c32 == 4) { va00 = ONES4; va01 = ONES4; va10 = ONES4; va11 = ONES4; }

            f32x16 sc0 = __builtin_amdgcn_mfma_f32_32x32x16_f16(
                __builtin_bit_cast(h8_t, ka0), __builtin_bit_cast(h8_t, qa0), z, 0, 0, 0);
            f32x16 sc1 = __builtin_amdgcn_mfma_f32_32x32x16_f16(
                __builtin_bit_cast(h8_t, ka1), __builtin_bit_cast(h8_t, qa1), z, 0, 0, 0);

            uint4 p00u, p01u, p10u, p11u;
            {
                float e[16];
#pragma unroll
                for (int r = 0; r < 16; ++r) e[r] = EXP2F(sc0[r]);
                p00u = make_uint4(pk16(e[0], e[1]),  pk16(e[2], e[3]),
                                  pk16(e[4], e[5]),  pk16(e[6], e[7]));
                p01u = make_uint4(pk16(e[8], e[9]),  pk16(e[10], e[11]),
                                  pk16(e[12], e[13]), pk16(e[14], e[15]));
            }
            {
                float e[16];
#pragma unroll
                for (int r = 0; r < 16; ++r) e[r] = EXP2F(sc1[r]);
                p10u = make_uint4(pk16(e[0], e[1]),  pk16(e[2], e[3]),
                                  pk16(e[4], e[5]),  pk16(e[6], e[7]));
                p11u = make_uint4(pk16(e[8], e[9]),  pk16(e[10], e[11]),
                                  pk16(e[12], e[13]), pk16(e[14], e[15]));
            }

            f32x16 pv0 = __builtin_amdgcn_mfma_f32_32x32x16_f16(
                __builtin_bit_cast(h8_t, va00), __builtin_bit_cast(h8_t, p00u), z, 0, 0, 0);
            pv0 = __builtin_amdgcn_mfma_f32_32x32x16_f16(
                __builtin_bit_cast(h8_t, va01), __builtin_bit_cast(h8_t, p01u), pv0, 0, 0, 0);
            f32x16 pv1 = __builtin_amdgcn_mfma_f32_32x32x16_f16(
                __builtin_bit_cast(h8_t, va10), __builtin_bit_cast(h8_t, p10u), z, 0, 0, 0);
            pv1 = __builtin_amdgcn_mfma_f32_32x32x16_f16(
                __builtin_bit_cast(h8_t, va11), __builtin_bit_cast(h8_t, p11u), pv1, 0, 0, 0);

            // denom at row 4 -> lane (c32,1) reg0; O[d] at lane (c32,0) regs0-3
            float s0 = __shfl(pv0[0], c32 + 32, 64);
            float s1 = __shfl(pv1[0], c32 + 32, 64);
            float r0 = RCPF(s0), r1 = RCPF(s1);
            if (lane < 32) {
                uint2 st0 = make_uint2(pk16(pv0[0] * r0, pv0[1] * r0),
                                       pk16(pv0[2] * r0, pv0[3] * r0));
                uint2 st1 = make_uint2(pk16(pv1[0] * r1, pv1[1] * r1),
                                       pk16(pv1[2] * r1, pv1[3] * r1));
                *(uint2*)(qs + t0 * LPITCH + c32 * 4) = st0;   // attended aliases qs
                *(uint2*)(qs + t1 * LPITCH + c32 * 4) = st1;
            }
        }
    }
    __syncthreads();

    // ---------------- Phase 3: output projection + bias (A=Wo, B=at) -------
    {
        h8_t af[4];
#pragma unroll
        for (int ks2 = 0; ks2 < 4; ++ks2) {
            af[ks2] = *(const h8_t*)(qs + c * LPITCH + ks2 * 32 + g * 8);
        }
#pragma unroll
        for (int i = 0; i < 4; ++i) {
            int nt = wave * 4 + i;
            const __fp16* wb = wpk + ((size_t)((3 * 8 + nt) * 4) * 64 + lane) * 8;
            f32x4 acc = {0.f, 0.f, 0.f, 0.f};
#pragma unroll
            for (int ks2 = 0; ks2 < 4; ++ks2) {
                h8_t b = *(const h8_t*)(wb + (size_t)ks2 * 64 * 8);
                acc = __builtin_amdgcn_mfma_f32_16x16x32_f16(b, af[ks2], acc, 0, 0, 0);
            }
            int col0 = nt * 16 + g * 4;           // C[m=w_row][n=token c]
            float4 b4 = *(const float4*)(bo + col0);
            float4 st = make_float4(acc[0] + b4.x, acc[1] + b4.y,
                                    acc[2] + b4.z, acc[3] + b4.w);
            *(float4*)(out + (size_t)(bt0 + c) * E + col0) = st;   // one dwordx4
        }
    }
}

// ---------------------------------------------------------------------------
extern "C" void kernel_launch(void* const* d_in, const int* in_sizes, int n_in,
                              void* d_out, int out_size, void* d_ws, size_t ws_size,
                              hipStream_t stream) {
    const float* x  = (const float*)d_in[0];
    const float* Wq = (const float*)d_in[1];
    const float* Wk = (const float*)d_in[2];
    const float* Wv = (const float*)d_in[3];
    const float* Wo = (const float*)d_in[4];
    const float* bo = (const float*)d_in[5];
    __fp16* wpk = (__fp16*)d_ws;   // 4*8*4*64*8 f16 = 128 KiB
    float* out = (float*)d_out;

    pack_w<<<32, 256, 0, stream>>>(Wq, Wk, Wv, Wo, wpk);
    mha_fused<<<TOKENS / BT, THREADS, 0, stream>>>(x, wpk, bo, out);
}